// Round 8
// baseline (420.680 us; speedup 1.0000x reference)
//
#include <hip/hip_runtime.h>
#include <hip/hip_bf16.h>
#include <math.h>

#define N_NODES  50000
#define N_EDGES  800000
#define E_TOT    850000   /* edges + self loops */
#define N_GRAPHS 64
#define N_LOCS   50
#define SCAN_B   ((N_NODES + 255) / 256)   /* 196 scan blocks */
#define TSTRIDE  128                       /* bf16 T row stride: 256B, 4 lines */
#define HSTRIDE  132                       /* f32 H row stride: 528B, 16B-aligned */
#define ASTRIDE  160                       /* bf16 A row stride: K=129 padded to 5 k-tiles of 32 */

#define EB_B     ((E_TOT + 255) / 256)     /* 3321 edge blocks */
#define GEMM0_B  ((N_NODES + 31) / 32)     /* 1563 layer-0 gemm blocks */
#define NPB3     85                        /* esed3: nodes per block */
#define RST3     136                       /* esed3 LDS row stride (u16): 272B, 4r bank spread */
#define ESED3_B  ((N_NODES + NPB3 - 1) / NPB3)  /* 589 */
#define POOL_B   ((N_NODES + 31) / 32)     /* 1563 pooling blocks */

typedef __hip_bfloat16 bf16;
typedef __attribute__((ext_vector_type(8))) short bf16x8;   // 8 bf16 payload (4 VGPR)
typedef __attribute__((ext_vector_type(4))) float f32x4;

// ---------------- static scratch ----------------
__device__ int      g_deg[N_NODES];
__device__ int      g_rowptr[N_NODES + 1];
__device__ int      g_slot[E_TOT];               // within-node sequence from deg atomic
__device__ int      g_csrc[E_TOT];               // CSR: src node per slot
__device__ float    g_Wp0[6 * 132];              // padded f32 weights, layer 0
__device__ __align__(256) unsigned short g_Tb[(size_t)N_NODES * TSTRIDE]; // T cols 0..127 (bf16)
__device__ float    g_Te[N_NODES];               // T col 128 (f32)
__device__ __align__(16) float g_H[(size_t)N_NODES * HSTRIDE]; // final layer output (f32)
// split-bf16 A for MFMA GEMMs (layers 1,2 input). hi + lo ~= f32 to 2^-18.
__device__ __align__(16) unsigned short g_Ah[(size_t)N_NODES * ASTRIDE];
__device__ __align__(16) unsigned short g_Al[(size_t)N_NODES * ASTRIDE];
// W packed in MFMA fragment order: [kt][nt][lane][8], hi/lo split
#define WQ1_N (5 * 9 * 64 * 8)    /* 23040: layer1, 9 N-tiles (cols 0..143, 129 real) */
#define WQ2_N (5 * 8 * 64 * 8)    /* 20480: layer2, 8 N-tiles (cols 0..127) */
__device__ __align__(16) unsigned short g_Wq1h[WQ1_N], g_Wq1l[WQ1_N];
__device__ __align__(16) unsigned short g_Wq2h[WQ2_N], g_Wq2l[WQ2_N];
__device__ float    g_es[N_NODES * 3];
__device__ float    g_ed[N_NODES * 3];
__device__ unsigned g_gmk[9];                    // per-layer global es max keys
__device__ float    g_gsum[N_GRAPHS * 128];
__device__ float    g_gcnt[N_GRAPHS];

// ---------------- helpers ----------------
__device__ __forceinline__ float lrelu(float x){ return x > 0.f ? x : 0.2f * x; }
__device__ __forceinline__ int   clampi(int v, int lo, int hi){ return v < lo ? lo : (v > hi ? hi : v); }
__device__ __forceinline__ float finz(float v){
    unsigned u = __float_as_uint(v);
    return ((u & 0x7F800000u) == 0x7F800000u) ? 0.f : v;   // NaN/inf -> 0
}
__device__ __forceinline__ unsigned short f2bu(float x){
    union { bf16 b; unsigned short u; } cv; cv.b = __float2bfloat16(x); return cv.u;
}
__device__ __forceinline__ float bu2f(unsigned short u){ return __uint_as_float(((unsigned)u) << 16); }
__device__ __forceinline__ unsigned fkey(float f){
    unsigned u = __float_as_uint(f);
    return (u & 0x80000000u) ? ~u : (u | 0x80000000u);
}
__device__ __forceinline__ float kinv(unsigned k){
    return __uint_as_float((k & 0x80000000u) ? (k ^ 0x80000000u) : ~k);
}
__device__ __forceinline__ float expc(float a){ return __expf(fminf(fmaxf(a, -80.f), 0.f)); }
__device__ __forceinline__ void edge_sd(const int* ei, int e, int& src, int& dst){
    if (e < N_EDGES){
        src = clampi(ei[e], 0, N_NODES - 1);
        dst = clampi(ei[N_EDGES + e], 0, N_NODES - 1);
    } else {
        src = dst = e - N_EDGES;
    }
}
// wave-uniform broadcast: lane index is uniform -> result in SGPR (no DS pipe)
#define RL_I(v, i) __builtin_amdgcn_readlane((v), (i))
#define RL_F(v, i) __uint_as_float((unsigned)__builtin_amdgcn_readlane((int)__float_as_uint(v), (i)))

// ---------------- fused preprocessing: zero + pad/pack all weights ----------
// [deg 50000][gsum 8192][gmk 9][Wp0 792][Wq1 23040][Wq2 20480]
#define PRE_TOT (N_NODES + N_GRAPHS*128 + 9 + 6*132 + WQ1_N + WQ2_N)
__global__ void k_pre(const float* __restrict__ W0, const float* __restrict__ W1,
                      const float* __restrict__ W2){
    int i = blockIdx.x * blockDim.x + threadIdx.x;
    if (i < N_NODES){ g_deg[i] = 0; return; }
    i -= N_NODES;
    if (i < N_GRAPHS * 128){ g_gsum[i] = 0.f; return; }
    i -= N_GRAPHS * 128;
    if (i < 9){ g_gmk[i] = 0u; return; }
    i -= 9;
    if (i < 6 * 132){
        int k = i / 132, c = i - k * 132;
        g_Wp0[i] = (c < 129) ? finz(W0[k * 129 + c]) : 0.f;
        return;
    }
    i -= 6 * 132;
    if (i < WQ1_N){
        int kt = i / 4608;             // 9*64*8
        int r1 = i - kt * 4608;
        int nt = r1 / 512;
        int r2 = r1 - nt * 512;
        int ln = r2 >> 3, j = r2 & 7;
        int k = kt * 32 + (ln >> 4) * 8 + j;
        int c = nt * 16 + (ln & 15);
        float v = (k < 129 && c < 129) ? finz(W1[k * 129 + c]) : 0.f;
        unsigned short h = f2bu(v);
        g_Wq1h[i] = h;
        g_Wq1l[i] = f2bu(v - bu2f(h));
        return;
    }
    i -= WQ1_N;
    if (i < WQ2_N){
        int kt = i / 4096;             // 8*64*8
        int r1 = i - kt * 4096;
        int nt = r1 / 512;
        int r2 = r1 - nt * 512;
        int ln = r2 >> 3, j = r2 & 7;
        int k = kt * 32 + (ln >> 4) * 8 + j;
        int c = nt * 16 + (ln & 15);
        float v = (k < 129 && c < 128) ? finz(W2[k * 128 + c]) : 0.f;
        unsigned short h = f2bu(v);
        g_Wq2h[i] = h;
        g_Wq2l[i] = f2bu(v - bu2f(h));
    }
}

// ---------------- fused: degree count (+slot) || layer-0 GEMM ---------------
__global__ __launch_bounds__(256)
void k_g0deg(const float* __restrict__ X, const int* __restrict__ ei){
    if (blockIdx.x < EB_B){
        int e = blockIdx.x * 256 + threadIdx.x;
        if (e >= E_TOT) return;
        int src, dst; edge_sd(ei, e, src, dst);
        (void)src;
        g_slot[e] = atomicAdd(&g_deg[dst], 1);   // within-node sequence
        return;
    }
    // ---- layer-0 GEMM: K=6, f32 VALU ----
    const int R = 4, CO = 129;
    const float* Wp = g_Wp0;
    int bid = blockIdx.x - EB_B;
    int tid = threadIdx.x;
    int rg = tid >> 5;
    int g  = tid & 31;
    int n0 = bid * (8 * R) + rg * R;
    const float4* wp = (const float4*)Wp;     // [rows][33] float4s
    float4 acc[R];
    float accE[R];
    #pragma unroll
    for (int r = 0; r < R; r++){ acc[r] = make_float4(0.f,0.f,0.f,0.f); accE[r] = 0.f; }

    const float* ar[R];
    #pragma unroll
    for (int r = 0; r < R; r++){
        int n = n0 + r;
        ar[r] = X + (size_t)(n < N_NODES ? n : N_NODES - 1) * 6;
    }
    #pragma unroll
    for (int k = 0; k < 6; k++){
        float4 w = wp[k * 33 + g];
        float we = (g == 0) ? Wp[k * 132 + 128] : 0.f;
        #pragma unroll
        for (int r = 0; r < R; r++){
            float a = ar[r][k];
            acc[r].x += a * w.x; acc[r].y += a * w.y;
            acc[r].z += a * w.z; acc[r].w += a * w.w;
            if (g == 0) accE[r] += a * we;
        }
    }

    #pragma unroll
    for (int r = 0; r < R; r++){
        int n = n0 + r;
        if (n >= N_NODES) break;
        unsigned* tw = (unsigned*)(g_Tb + (size_t)n * TSTRIDE);
        tw[g * 2]     = ((unsigned)f2bu(finz(acc[r].x)) ) | ((unsigned)f2bu(finz(acc[r].y)) << 16);
        tw[g * 2 + 1] = ((unsigned)f2bu(finz(acc[r].z)) ) | ((unsigned)f2bu(finz(acc[r].w)) << 16);
        if (CO > 128 && g == 0) g_Te[n] = finz(accE[r]);
    }
}

// ---------------- single-kernel CSR scan ------------------------------------
// Block b independently sums g_deg[0 .. b*256) (20 MB L2 total across grid),
// then local-scans its 256 degrees -- no cross-block dependency, one launch.
__global__ __launch_bounds__(256)
void k_scan(){
    __shared__ int rs[256];
    __shared__ int s[256];
    int b = blockIdx.x, tid = threadIdx.x;
    int pre = 0;
    for (int i = tid; i < b * 256; i += 256) pre += g_deg[i];
    rs[tid] = pre;
    __syncthreads();
    #pragma unroll
    for (int off = 128; off >= 1; off >>= 1){
        if (tid < off) rs[tid] += rs[tid + off];
        __syncthreads();
    }
    int base = rs[0];
    int i = b * 256 + tid;
    int v = (i < N_NODES) ? g_deg[i] : 0;
    s[tid] = v;
    __syncthreads();
    for (int off = 1; off < 256; off <<= 1){
        int add = (tid >= off) ? s[tid - off] : 0;
        __syncthreads();
        s[tid] += add;
        __syncthreads();
    }
    if (i < N_NODES) g_rowptr[i] = base + s[tid] - v;
    if (b == 0 && tid == 0) g_rowptr[N_NODES] = E_TOT;
}

// ---------------- esed H=3: LDS-staged rows, bit-exact o-order --------------
__device__ __forceinline__ void esed3_body(const float* __restrict__ as,
                                           const float* __restrict__ ad,
                                           int base, int bid){
    __shared__ unsigned short rows[NPB3 * RST3];
    __shared__ unsigned sm[3];
    int tid = threadIdx.x;
    if (tid < 3) sm[tid] = 0u;
    int n0 = bid * NPB3;
    for (int ch = tid; ch < NPB3 * 16; ch += 256){
        int r = ch >> 4, k = ch & 15;
        int n = n0 + r; if (n >= N_NODES) n = N_NODES - 1;
        *(uint4*)&rows[r * RST3 + k * 8] =
            *(const uint4*)(g_Tb + (size_t)n * TSTRIDE + k * 8);
    }
    __syncthreads();
    int idx = n0 * 3 + tid;
    if (tid < NPB3 * 3 && idx < N_NODES * 3){
        int r = tid / 3, h = tid - r * 3;
        const unsigned short* rw = rows + r * RST3;
        float a = 0.f, b = 0.f;
        #pragma unroll 4
        for (int o = 0; o < 43; o++){
            int col = h * 43 + o;
            float v = (col < 128) ? bu2f(rw[col]) : finz(g_Te[n0 + r]);
            a += v * finz(as[h * 43 + o]);
            b += v * finz(ad[h * 43 + o]);
        }
        a = finz(a); b = finz(b);
        g_es[idx] = a; g_ed[idx] = b;
        atomicMax(&sm[h], fkey(a));
    }
    __syncthreads();
    if (tid < 3) atomicMax(&g_gmk[base + tid], sm[tid]);
}

__global__ __launch_bounds__(256)
void k_esed3(const float* __restrict__ as, const float* __restrict__ ad, int base){
    esed3_body(as, ad, base, blockIdx.x);
}

// ---------------- fused: atomic-free CSR fill || esed3 layer-0 --------------
__global__ __launch_bounds__(256)
void k_esfill(const float* __restrict__ as, const float* __restrict__ ad,
              const int* __restrict__ ei){
    if (blockIdx.x < EB_B){
        int e = blockIdx.x * 256 + threadIdx.x;
        if (e >= E_TOT) return;
        int src, dst; edge_sd(ei, e, src, dst);
        int pos = clampi(g_rowptr[dst] + g_slot[e], 0, E_TOT - 1);
        g_csrc[pos] = src;
        return;
    }
    esed3_body(as, ad, 0, blockIdx.x - EB_B);
}

// ---------------- esed H=1 (layer 2): register row, static unroll -----------
__global__ __launch_bounds__(256)
void k_esedR(const float* __restrict__ as, const float* __restrict__ ad, int base){
    __shared__ unsigned sm[1];
    int tid = threadIdx.x;
    if (tid == 0) sm[0] = 0u;
    __syncthreads();
    int n = blockIdx.x * 256 + tid;
    bool act = n < N_NODES;
    int nn = act ? n : N_NODES - 1;
    const uint4* rp = (const uint4*)(g_Tb + (size_t)nn * TSTRIDE);
    float a = 0.f, b = 0.f;
    #pragma unroll
    for (int k = 0; k < 16; k++){
        uint4 ch = rp[k];
        unsigned dw[4] = {ch.x, ch.y, ch.z, ch.w};
        #pragma unroll
        for (int j = 0; j < 4; j++){
            unsigned d = dw[j];
            int o = k * 8 + j * 2;
            float v0 = bu2f((unsigned short)(d & 0xFFFFu));
            float v1 = bu2f((unsigned short)(d >> 16));
            a += v0 * finz(as[o]);     b += v0 * finz(ad[o]);
            a += v1 * finz(as[o + 1]); b += v1 * finz(ad[o + 1]);
        }
    }
    if (act){
        a = finz(a); b = finz(b);
        g_es[n] = a; g_ed[n] = b;
        atomicMax(&sm[0], fkey(a));
    }
    __syncthreads();
    if (tid == 0) atomicMax(&g_gmk[base], sm[0]);
}

// ---------------- layers 1,2 GEMM: split-bf16 MFMA --------------------------
// D = Ahi*Whi + Alo*Whi + Ahi*Wlo  (error ~2^-18, numerically ~f32).
template<int NT, bool HASE>   // NT=9+E for layer1, NT=8 for layer2
__global__ __launch_bounds__(256, 3)
void k_gmm(){
    const unsigned short* Wh = HASE ? g_Wq1h : g_Wq2h;
    const unsigned short* Wl = HASE ? g_Wq1l : g_Wq2l;
    int lane = threadIdx.x & 63, wv = threadIdx.x >> 6;
    int row0 = blockIdx.x * 64 + wv * 16;
    int rl = row0 + (lane & 15);
    if (rl >= N_NODES) rl = N_NODES - 1;
    const bf16x8* Ah = (const bf16x8*)(g_Ah + (size_t)rl * ASTRIDE);
    const bf16x8* Al = (const bf16x8*)(g_Al + (size_t)rl * ASTRIDE);
    int ao = lane >> 4;

    f32x4 acc[NT] = {};
    #pragma unroll
    for (int kt = 0; kt < 5; kt++){
        bf16x8 ah = Ah[kt * 4 + ao];
        bf16x8 al = Al[kt * 4 + ao];
        const bf16x8* wh = (const bf16x8*)Wh + (size_t)(kt * NT) * 64 + lane;
        const bf16x8* wl = (const bf16x8*)Wl + (size_t)(kt * NT) * 64 + lane;
        #pragma unroll
        for (int t = 0; t < NT; t++){
            bf16x8 bh = wh[t * 64];
            bf16x8 bl = wl[t * 64];
            acc[t] = __builtin_amdgcn_mfma_f32_16x16x32_bf16(ah, bh, acc[t], 0, 0, 0);
            acc[t] = __builtin_amdgcn_mfma_f32_16x16x32_bf16(al, bh, acc[t], 0, 0, 0);
            acc[t] = __builtin_amdgcn_mfma_f32_16x16x32_bf16(ah, bl, acc[t], 0, 0, 0);
        }
    }

    int rq = row0 + (lane >> 4) * 4;
    int c  = lane & 15;
    #pragma unroll
    for (int t = 0; t < NT; t++){
        int col = t * 16 + c;
        #pragma unroll
        for (int q = 0; q < 4; q++){
            int rr = rq + q;
            if (rr >= N_NODES) continue;
            float v = finz(acc[t][q]);
            if (col < 128)            g_Tb[(size_t)rr * TSTRIDE + col] = f2bu(v);
            else if (HASE && col == 128) g_Te[rr] = v;
        }
    }
}

// ------- FUSED softmax+gather, single edge sweep ----------------------------
// Issue-slot-trimmed inner loop. Z[h] denominators come from the zA of lanes
// {0,22,43} (identical += sequences in t-order) via epilogue readlanes; the
// E-column is accumulated by lane 63 whose wB == w[t,2], eliminating the w2
// ds_read; H=1 uses readlane(w,t) instead of LDS. All retained accumulators
// are bit-identical in value and order to the verified-passing kernel.
// WRITEA: layers 0,1 write split-bf16 A rows; layer 2 writes f32 H.
template<int H, int O, int C, bool LEAKY, bool WRITEA>
__global__ __launch_bounds__(256)
void k_fgat(const float* __restrict__ bias, int base){
    const int CH = 64 / H;               // 21 for H=3, 64 for H=1
    __shared__ float lw[4][64];
    int wv = threadIdx.x >> 6, lane = threadIdx.x & 63;
    int n = blockIdx.x * 4 + wv;
    if (n >= N_NODES) return;
    int r0 = clampi(g_rowptr[n], 0, E_TOT);
    int r1 = clampi(g_rowptr[n + 1], r0, E_TOT);

    const int jmine = lane / H;
    const int hmine = lane - jmine * H;
    const float edm = finz(g_ed[n * H + hmine]);
    const float mxm = lrelu(finz(kinv(g_gmk[base + hmine])) + edm);  // upper bound
    const unsigned* tb = (const unsigned*)g_Tb;   // row = 64 dwords

    const int c0 = 2 * lane, c1 = 2 * lane + 1;
    const int h0 = c0 / O, h1 = c1 / O;
    float* lwp = lw[wv];

    float a0 = 0.f, a1 = 0.f, zA = 0.f, A2 = 0.f;

// per-edge body. H=3: wA/wB via LDS (2 ds_read); lane63's wB==w[t,2] feeds A2.
// H=1: weight via readlane (SGPR, no DS). t-order of every sum preserved.
#define EDGE(tt, pv, ss) { \
    float x0 = __uint_as_float((pv) << 16); \
    float x1 = __uint_as_float((pv) & 0xFFFF0000u); \
    if (H > 1){ \
        float wA = lwp[(tt) * H + h0]; \
        float wB = lwp[(tt) * H + h1]; \
        a0 += wA * x0; zA += wA; \
        a1 += wB * x1; \
        if (C > 128){ float te = finz(g_Te[ss]); A2 += wB * te; } \
    } else { \
        float wA = RL_F(w, (tt)); \
        a0 += wA * x0; zA += wA; \
        a1 += wA * x1; \
    } \
}

    for (int bse = r0; bse < r1; bse += CH){
        int m = r1 - bse; if (m > CH) m = CH;
        // phase A: cooperative weight computation (1 exp per lane)
        float w = 0.f; int sA = 0;
        if (jmine < m){
            sA = clampi(g_csrc[bse + jmine], 0, N_NODES - 1);
            w = expc(lrelu(finz(g_es[sA * H + hmine]) + edm) - mxm);
        }
        if (H > 1) lwp[lane] = w;   // wave-private row; same-wave DS order ok
        // phase B: 4 row loads in flight; src via readlane (SGPR addressing)
        int t = 0;
        for (; t + 4 <= m; t += 4){
            int s0 = RL_I(sA, (t + 0) * H);
            int s1 = RL_I(sA, (t + 1) * H);
            int s2 = RL_I(sA, (t + 2) * H);
            int s3 = RL_I(sA, (t + 3) * H);
            unsigned pv0 = tb[(size_t)s0 * 64 + lane];
            unsigned pv1 = tb[(size_t)s1 * 64 + lane];
            unsigned pv2 = tb[(size_t)s2 * 64 + lane];
            unsigned pv3 = tb[(size_t)s3 * 64 + lane];
            EDGE(t + 0, pv0, s0)
            EDGE(t + 1, pv1, s1)
            EDGE(t + 2, pv2, s2)
            EDGE(t + 3, pv3, s3)
        }
        for (; t < m; ++t){
            int s0 = RL_I(sA, t * H);
            unsigned pv0 = tb[(size_t)s0 * 64 + lane];
            EDGE(t, pv0, s0)
        }
    }
#undef EDGE

    // head-class denominators: lanes 0/22/43 hold Z[0]/Z[1]/Z[2] as zA
    // (identical accumulation sequences to the old per-lane zB/z2).
    float zB;
    if (H == 1){
        zB = zA;
    } else {
        float sz0 = RL_F(zA, 0);
        float sz1 = RL_F(zA, 22);
        float sz2 = RL_F(zA, 43);
        zB = (h1 == 0) ? sz0 : ((h1 == 1) ? sz1 : sz2);
    }

    float o0 = finz(a0 / (zA + 1e-16f)) + finz(bias[c0]);
    float o1 = finz(a1 / (zB + 1e-16f)) + finz(bias[c1]);
    if (LEAKY){ o0 = lrelu(o0); o1 = lrelu(o1); }
    o0 = finz(o0); o1 = finz(o1);
    float o2 = 0.f;
    if (C > 128){
        // meaningful on lane 63 only (wB == w[t,2], zB == Z[2] there)
        o2 = finz(A2 / (zB + 1e-16f)) + finz(bias[128]);
        if (LEAKY) o2 = lrelu(o2);
        o2 = finz(o2);
    }

    if (WRITEA){
        // split f32 -> bf16 hi + bf16 lo; pad cols 128..159 (E col + zeros)
        unsigned short hh0 = f2bu(o0), hh1 = f2bu(o1);
        unsigned short ll0 = f2bu(o0 - bu2f(hh0)), ll1 = f2bu(o1 - bu2f(hh1));
        unsigned* ah = (unsigned*)(g_Ah + (size_t)n * ASTRIDE);
        unsigned* al = (unsigned*)(g_Al + (size_t)n * ASTRIDE);
        ah[lane] = (unsigned)hh0 | ((unsigned)hh1 << 16);
        al[lane] = (unsigned)ll0 | ((unsigned)ll1 << 16);
        if (lane >= 1 && lane < 16){ ah[64 + lane] = 0u; al[64 + lane] = 0u; }
        if (C > 128){
            if (lane == 63){
                unsigned short h2 = f2bu(o2);
                ah[64] = (unsigned)h2;
                al[64] = (unsigned)f2bu(o2 - bu2f(h2));
            }
        } else if (lane == 0){
            ah[64] = 0u; al[64] = 0u;
        }
    } else {
        g_H[(size_t)n * HSTRIDE + c0] = o0;
        g_H[(size_t)n * HSTRIDE + c1] = o1;
        if (C > 128 && lane == 63) g_H[(size_t)n * HSTRIDE + 128] = o2;
    }
}

// ---------------- fused: pooling || location MLP ----------------------------
__global__ __launch_bounds__(256)
void k_poolloc(const int* __restrict__ batch, const float* __restrict__ loc,
               const float* __restrict__ Wl1, const float* __restrict__ bl1,
               const float* __restrict__ Wl2, const float* __restrict__ bl2,
               float* __restrict__ out){
    if (blockIdx.x < POOL_B){
        int c = threadIdx.x & 127;
        int n0 = blockIdx.x * 32 + (threadIdx.x >> 7) * 16;
        int bprev = -1; float acc = 0.f;
        for (int j = 0; j < 16; j++){
            int n = n0 + j;
            if (n >= N_NODES) break;
            int b = clampi(batch[n], 0, N_GRAPHS - 1);
            if (b != bprev){
                if (bprev >= 0) atomicAdd(&g_gsum[bprev * 128 + c], acc);
                acc = 0.f; bprev = b;
            }
            acc += finz(g_H[(size_t)n * HSTRIDE + c]);
        }
        if (bprev >= 0) atomicAdd(&g_gsum[bprev * 128 + c], acc);
        return;
    }
    int b = blockIdx.x - POOL_B, t = threadIdx.x;
    if (b == N_GRAPHS){   // per-graph node counts via binary search
        if (t < N_GRAPHS){
            int lo = 0, hi = N_NODES;
            while (lo < hi){ int mid = (lo + hi) >> 1; if (batch[mid] <  t) lo = mid + 1; else hi = mid; }
            int start = lo;
            lo = 0; hi = N_NODES;
            while (lo < hi){ int mid = (lo + hi) >> 1; if (batch[mid] <= t) lo = mid + 1; else hi = mid; }
            g_gcnt[t] = (float)(lo - start);
        }
        return;
    }
    __shared__ float hs[256];
    float w0 = finz(Wl1[t]);
    float w1 = finz(Wl1[256 + t]);
    float bb = finz(bl1[t]);
    float s = 0.f;
    #pragma unroll 5
    for (int l = 0; l < N_LOCS; l++){
        float x0 = finz(loc[((size_t)b * N_LOCS + l) * 2]);
        float x1 = finz(loc[((size_t)b * N_LOCS + l) * 2 + 1]);
        s += tanhf(x0 * w0 + x1 * w1 + bb);
    }
    hs[t] = s;
    __syncthreads();
    if (t < 128){
        float acc = 0.f;
        #pragma unroll 8
        for (int j = 0; j < 256; j++) acc += hs[j] * finz(Wl2[(size_t)j * 128 + t]);
        out[(size_t)b * 256 + 128 + t] = finz(acc * (1.f / (float)N_LOCS) + finz(bl2[t]));
    }
}

// output is float32 (established r13/r14)
__global__ void k_fin(float* __restrict__ out){
    int idx = blockIdx.x * blockDim.x + threadIdx.x;
    if (idx >= N_GRAPHS * 128) return;
    int b = idx >> 7, c = idx & 127;
    out[b * 256 + c] = finz(finz(g_gsum[idx]) / fmaxf(g_gcnt[b], 1.f));
}

// ---------------- launch ----------------
extern "C" void kernel_launch(void* const* d_in, const int* in_sizes, int n_in,
                              void* d_out, int out_size, void* d_ws, size_t ws_size,
                              hipStream_t stream){
    static const int want[20] = {300000, 6400, 1600000, 50000,
                                 774, 129, 129, 129,
                                 16641, 129, 129, 129,
                                 16512, 128, 128, 128,
                                 512, 256, 32768, 128};
    const void* P[20];
    bool assigned[20];
    for (int s = 0; s < 20; s++){ P[s] = nullptr; assigned[s] = false; }
    bool ok = (n_in == 20);
    if (ok){
        for (int i = 0; i < 20; i++){
            int sz = in_sizes[i], hit = -1;
            for (int s = 0; s < 20; s++)
                if (!assigned[s] && want[s] == sz){ hit = s; break; }
            if (hit < 0){ ok = false; break; }
            P[hit] = d_in[i]; assigned[hit] = true;
        }
        for (int s = 0; s < 20 && ok; s++) if (!assigned[s]) ok = false;
    }
    if (!ok) for (int s = 0; s < 20 && s < n_in; s++) P[s] = d_in[s];

    const float* x    = (const float*)P[0];
    const float* loc  = (const float*)P[1];
    const int*   ei   = (const int*)  P[2];
    const int*   batch= (const int*)  P[3];
    const float* W0   = (const float*)P[4];
    const float* as0  = (const float*)P[5];
    const float* ad0  = (const float*)P[6];
    const float* b0   = (const float*)P[7];
    const float* W1   = (const float*)P[8];
    const float* as1  = (const float*)P[9];
    const float* ad1  = (const float*)P[10];
    const float* b1   = (const float*)P[11];
    const float* W2   = (const float*)P[12];
    const float* as2  = (const float*)P[13];
    const float* ad2  = (const float*)P[14];
    const float* b2   = (const float*)P[15];
    const float* Wl1  = (const float*)P[16];
    const float* bl1  = (const float*)P[17];
    const float* Wl2  = (const float*)P[18];
    const float* bl2  = (const float*)P[19];
    float* out = (float*)d_out;
    (void)d_ws; (void)ws_size; (void)out_size;

    const int MFMA_B  = (N_NODES + 63) / 64;   // 64 rows/block (4 waves x 16)
    const int GB = (N_NODES + 3) / 4;

    k_pre    <<<(PRE_TOT + 255) / 256, 256, 0, stream>>>(W0, W1, W2);
    k_g0deg  <<<EB_B + GEMM0_B, 256, 0, stream>>>(x, ei);   // deg+slot || gemm0
    k_scan   <<<SCAN_B, 256, 0, stream>>>();
    k_esfill <<<EB_B + ESED3_B, 256, 0, stream>>>(as0, ad0, ei); // fill || esed0

    // layer 0
    k_fgat<3, 43, 129, true, true><<<GB, 256, 0, stream>>>(b0, 0);

    // layer 1 (MFMA split-bf16)
    k_gmm<9, true><<<MFMA_B, 256, 0, stream>>>();
    k_esed3<<<ESED3_B, 256, 0, stream>>>(as1, ad1, 3);
    k_fgat<3, 43, 129, true, true><<<GB, 256, 0, stream>>>(b1, 3);

    // layer 2 (MFMA split-bf16)
    k_gmm<8, false><<<MFMA_B, 256, 0, stream>>>();
    k_esedR<<<(N_NODES + 255) / 256, 256, 0, stream>>>(as2, ad2, 6);
    k_fgat<1, 128, 128, false, false><<<GB, 256, 0, stream>>>(b2, 6);

    // pooling + location + output
    k_poolloc<<<POOL_B + N_GRAPHS + 1, 256, 0, stream>>>(batch, loc, Wl1, bl1, Wl2, bl2, out);
    k_fin  <<<(N_GRAPHS * 128 + 255) / 256, 256, 0, stream>>>(out);
}

// Round 9
// 385.720 us; speedup vs baseline: 1.0906x; 1.0906x over previous
//
#include <hip/hip_runtime.h>
#include <hip/hip_bf16.h>
#include <math.h>

#define N_NODES  50000
#define N_EDGES  800000
#define E_TOT    850000   /* edges + self loops */
#define N_GRAPHS 64
#define N_LOCS   50
#define SCAN_B   ((N_NODES + 255) / 256)   /* 196 scan blocks */
#define TSTRIDE  128                       /* bf16 T row stride: 256B, 4 lines */
#define HSTRIDE  132                       /* f32 H row stride: 528B, 16B-aligned */
#define ASTRIDE  160                       /* bf16 A row stride: K=129 padded to 5 k-tiles of 32 */

#define EB_B     ((E_TOT + 255) / 256)     /* 3321 edge blocks */
#define GEMM0_B  ((N_NODES + 31) / 32)     /* 1563 layer-0 gemm blocks */
#define NPB3     85                        /* esed3: nodes per block */
#define RST3     136                       /* esed3 LDS row stride (u16): 272B, 4r bank spread */
#define ESED3_B  ((N_NODES + NPB3 - 1) / NPB3)  /* 589 */
#define POOL_B   ((N_NODES + 31) / 32)     /* 1563 pooling blocks */

typedef __hip_bfloat16 bf16;
typedef __attribute__((ext_vector_type(8))) short bf16x8;   // 8 bf16 payload (4 VGPR)
typedef __attribute__((ext_vector_type(4))) float f32x4;

// ---------------- static scratch ----------------
__device__ int      g_deg[N_NODES];
__device__ int      g_rowptr[N_NODES + 1];
__device__ int      g_bsum[SCAN_B];
__device__ int      g_slot[E_TOT];               // within-node sequence from deg atomic
__device__ int      g_csrc[E_TOT];               // CSR: src node per slot
__device__ float    g_Wp0[6 * 132];              // padded f32 weights, layer 0
__device__ __align__(256) unsigned short g_Tb[(size_t)N_NODES * TSTRIDE]; // T cols 0..127 (bf16)
__device__ float    g_Te[N_NODES];               // T col 128 (f32)
__device__ __align__(16) float g_H[(size_t)N_NODES * HSTRIDE]; // final layer output (f32)
// split-bf16 A for MFMA GEMMs (layers 1,2 input). hi + lo ~= f32 to 2^-18.
__device__ __align__(16) unsigned short g_Ah[(size_t)N_NODES * ASTRIDE];
__device__ __align__(16) unsigned short g_Al[(size_t)N_NODES * ASTRIDE];
// W packed in MFMA fragment order: [kt][nt][lane][8], hi/lo split
#define WQ1_N (5 * 9 * 64 * 8)    /* 23040: layer1, 9 N-tiles (cols 0..143, 129 real) */
#define WQ2_N (5 * 8 * 64 * 8)    /* 20480: layer2, 8 N-tiles (cols 0..127) */
__device__ __align__(16) unsigned short g_Wq1h[WQ1_N], g_Wq1l[WQ1_N];
__device__ __align__(16) unsigned short g_Wq2h[WQ2_N], g_Wq2l[WQ2_N];
__device__ float    g_es[N_NODES * 3];
__device__ float    g_ed[N_NODES * 3];
__device__ unsigned g_gmk[9];                    // per-layer global es max keys
__device__ float    g_gsum[N_GRAPHS * 128];
__device__ float    g_gcnt[N_GRAPHS];

// ---------------- helpers ----------------
__device__ __forceinline__ float lrelu(float x){ return x > 0.f ? x : 0.2f * x; }
__device__ __forceinline__ int   clampi(int v, int lo, int hi){ return v < lo ? lo : (v > hi ? hi : v); }
__device__ __forceinline__ float finz(float v){
    unsigned u = __float_as_uint(v);
    return ((u & 0x7F800000u) == 0x7F800000u) ? 0.f : v;   // NaN/inf -> 0
}
__device__ __forceinline__ unsigned short f2bu(float x){
    union { bf16 b; unsigned short u; } cv; cv.b = __float2bfloat16(x); return cv.u;
}
__device__ __forceinline__ float bu2f(unsigned short u){ return __uint_as_float(((unsigned)u) << 16); }
__device__ __forceinline__ unsigned fkey(float f){
    unsigned u = __float_as_uint(f);
    return (u & 0x80000000u) ? ~u : (u | 0x80000000u);
}
__device__ __forceinline__ float kinv(unsigned k){
    return __uint_as_float((k & 0x80000000u) ? (k ^ 0x80000000u) : ~k);
}
__device__ __forceinline__ float expc(float a){ return __expf(fminf(fmaxf(a, -80.f), 0.f)); }
__device__ __forceinline__ void edge_sd(const int* ei, int e, int& src, int& dst){
    if (e < N_EDGES){
        src = clampi(ei[e], 0, N_NODES - 1);
        dst = clampi(ei[N_EDGES + e], 0, N_NODES - 1);
    } else {
        src = dst = e - N_EDGES;
    }
}
// wave-uniform broadcast: lane index is uniform -> result in SGPR (no DS pipe)
#define RL_I(v, i) __builtin_amdgcn_readlane((v), (i))
#define RL_F(v, i) __uint_as_float((unsigned)__builtin_amdgcn_readlane((int)__float_as_uint(v), (i)))

// ---------------- fused preprocessing: zero + pad/pack all weights ----------
// [deg 50000][gsum 8192][gmk 9][Wp0 792][Wq1 23040][Wq2 20480]
#define PRE_TOT (N_NODES + N_GRAPHS*128 + 9 + 6*132 + WQ1_N + WQ2_N)
__global__ void k_pre(const float* __restrict__ W0, const float* __restrict__ W1,
                      const float* __restrict__ W2){
    int i = blockIdx.x * blockDim.x + threadIdx.x;
    if (i < N_NODES){ g_deg[i] = 0; return; }
    i -= N_NODES;
    if (i < N_GRAPHS * 128){ g_gsum[i] = 0.f; return; }
    i -= N_GRAPHS * 128;
    if (i < 9){ g_gmk[i] = 0u; return; }
    i -= 9;
    if (i < 6 * 132){
        int k = i / 132, c = i - k * 132;
        g_Wp0[i] = (c < 129) ? finz(W0[k * 129 + c]) : 0.f;
        return;
    }
    i -= 6 * 132;
    if (i < WQ1_N){
        int kt = i / 4608;             // 9*64*8
        int r1 = i - kt * 4608;
        int nt = r1 / 512;
        int r2 = r1 - nt * 512;
        int ln = r2 >> 3, j = r2 & 7;
        int k = kt * 32 + (ln >> 4) * 8 + j;
        int c = nt * 16 + (ln & 15);
        float v = (k < 129 && c < 129) ? finz(W1[k * 129 + c]) : 0.f;
        unsigned short h = f2bu(v);
        g_Wq1h[i] = h;
        g_Wq1l[i] = f2bu(v - bu2f(h));
        return;
    }
    i -= WQ1_N;
    if (i < WQ2_N){
        int kt = i / 4096;             // 8*64*8
        int r1 = i - kt * 4096;
        int nt = r1 / 512;
        int r2 = r1 - nt * 512;
        int ln = r2 >> 3, j = r2 & 7;
        int k = kt * 32 + (ln >> 4) * 8 + j;
        int c = nt * 16 + (ln & 15);
        float v = (k < 129 && c < 128) ? finz(W2[k * 128 + c]) : 0.f;
        unsigned short h = f2bu(v);
        g_Wq2h[i] = h;
        g_Wq2l[i] = f2bu(v - bu2f(h));
    }
}

// ---------------- fused: degree count (+slot) || layer-0 GEMM ---------------
__global__ __launch_bounds__(256)
void k_g0deg(const float* __restrict__ X, const int* __restrict__ ei){
    if (blockIdx.x < EB_B){
        int e = blockIdx.x * 256 + threadIdx.x;
        if (e >= E_TOT) return;
        int src, dst; edge_sd(ei, e, src, dst);
        (void)src;
        g_slot[e] = atomicAdd(&g_deg[dst], 1);   // within-node sequence
        return;
    }
    // ---- layer-0 GEMM: K=6, f32 VALU ----
    const int R = 4, CO = 129;
    const float* Wp = g_Wp0;
    int bid = blockIdx.x - EB_B;
    int tid = threadIdx.x;
    int rg = tid >> 5;
    int g  = tid & 31;
    int n0 = bid * (8 * R) + rg * R;
    const float4* wp = (const float4*)Wp;     // [rows][33] float4s
    float4 acc[R];
    float accE[R];
    #pragma unroll
    for (int r = 0; r < R; r++){ acc[r] = make_float4(0.f,0.f,0.f,0.f); accE[r] = 0.f; }

    const float* ar[R];
    #pragma unroll
    for (int r = 0; r < R; r++){
        int n = n0 + r;
        ar[r] = X + (size_t)(n < N_NODES ? n : N_NODES - 1) * 6;
    }
    #pragma unroll
    for (int k = 0; k < 6; k++){
        float4 w = wp[k * 33 + g];
        float we = (g == 0) ? Wp[k * 132 + 128] : 0.f;
        #pragma unroll
        for (int r = 0; r < R; r++){
            float a = ar[r][k];
            acc[r].x += a * w.x; acc[r].y += a * w.y;
            acc[r].z += a * w.z; acc[r].w += a * w.w;
            if (g == 0) accE[r] += a * we;
        }
    }

    #pragma unroll
    for (int r = 0; r < R; r++){
        int n = n0 + r;
        if (n >= N_NODES) break;
        unsigned* tw = (unsigned*)(g_Tb + (size_t)n * TSTRIDE);
        tw[g * 2]     = ((unsigned)f2bu(finz(acc[r].x)) ) | ((unsigned)f2bu(finz(acc[r].y)) << 16);
        tw[g * 2 + 1] = ((unsigned)f2bu(finz(acc[r].z)) ) | ((unsigned)f2bu(finz(acc[r].w)) << 16);
        if (CO > 128 && g == 0) g_Te[n] = finz(accE[r]);
    }
}

// ---------------- CSR scan (2 kernels, verified-fast R7 version) ------------
__global__ void k_scan1(){
    __shared__ int s[256];
    int i = blockIdx.x * 256 + threadIdx.x;
    int v = (i < N_NODES) ? g_deg[i] : 0;
    s[threadIdx.x] = v;
    __syncthreads();
    for (int off = 1; off < 256; off <<= 1){
        int add = (threadIdx.x >= off) ? s[threadIdx.x - off] : 0;
        __syncthreads();
        s[threadIdx.x] += add;
        __syncthreads();
    }
    if (threadIdx.x == 255) g_bsum[blockIdx.x] = s[255];
    if (i < N_NODES) g_rowptr[i] = s[threadIdx.x] - v;
}

// merged scan2+scan3: SCAN_B (=196) < 256, so each block reduces its own
// block-prefix of g_bsum in LDS. rowptr[N] = E_TOT statically.
__global__ __launch_bounds__(256)
void k_scan23(){
    __shared__ int red[256];
    int b = blockIdx.x, tid = threadIdx.x;
    red[tid] = (tid < b) ? g_bsum[tid] : 0;     // tid < b <= 195 < SCAN_B
    __syncthreads();
    #pragma unroll
    for (int off = 128; off >= 1; off >>= 1){
        if (tid < off) red[tid] += red[tid + off];
        __syncthreads();
    }
    int S = red[0];
    int i = b * 256 + tid;
    if (i < N_NODES) g_rowptr[i] += S;
    if (b == 0 && tid == 0) g_rowptr[N_NODES] = E_TOT;
}

// ---------------- esed H=3: LDS-staged rows, bit-exact o-order --------------
__device__ __forceinline__ void esed3_body(const float* __restrict__ as,
                                           const float* __restrict__ ad,
                                           int base, int bid){
    __shared__ unsigned short rows[NPB3 * RST3];
    __shared__ unsigned sm[3];
    int tid = threadIdx.x;
    if (tid < 3) sm[tid] = 0u;
    int n0 = bid * NPB3;
    for (int ch = tid; ch < NPB3 * 16; ch += 256){
        int r = ch >> 4, k = ch & 15;
        int n = n0 + r; if (n >= N_NODES) n = N_NODES - 1;
        *(uint4*)&rows[r * RST3 + k * 8] =
            *(const uint4*)(g_Tb + (size_t)n * TSTRIDE + k * 8);
    }
    __syncthreads();
    int idx = n0 * 3 + tid;
    if (tid < NPB3 * 3 && idx < N_NODES * 3){
        int r = tid / 3, h = tid - r * 3;
        const unsigned short* rw = rows + r * RST3;
        float a = 0.f, b = 0.f;
        #pragma unroll 4
        for (int o = 0; o < 43; o++){
            int col = h * 43 + o;
            float v = (col < 128) ? bu2f(rw[col]) : finz(g_Te[n0 + r]);
            a += v * finz(as[h * 43 + o]);
            b += v * finz(ad[h * 43 + o]);
        }
        a = finz(a); b = finz(b);
        g_es[idx] = a; g_ed[idx] = b;
        atomicMax(&sm[h], fkey(a));
    }
    __syncthreads();
    if (tid < 3) atomicMax(&g_gmk[base + tid], sm[tid]);
}

__global__ __launch_bounds__(256)
void k_esed3(const float* __restrict__ as, const float* __restrict__ ad, int base){
    esed3_body(as, ad, base, blockIdx.x);
}

// ---------------- fused: atomic-free CSR fill || esed3 layer-0 --------------
__global__ __launch_bounds__(256)
void k_esfill(const float* __restrict__ as, const float* __restrict__ ad,
              const int* __restrict__ ei){
    if (blockIdx.x < EB_B){
        int e = blockIdx.x * 256 + threadIdx.x;
        if (e >= E_TOT) return;
        int src, dst; edge_sd(ei, e, src, dst);
        int pos = clampi(g_rowptr[dst] + g_slot[e], 0, E_TOT - 1);
        g_csrc[pos] = src;
        return;
    }
    esed3_body(as, ad, 0, blockIdx.x - EB_B);
}

// ---------------- esed H=1 (layer 2): register row, static unroll -----------
__global__ __launch_bounds__(256)
void k_esedR(const float* __restrict__ as, const float* __restrict__ ad, int base){
    __shared__ unsigned sm[1];
    int tid = threadIdx.x;
    if (tid == 0) sm[0] = 0u;
    __syncthreads();
    int n = blockIdx.x * 256 + tid;
    bool act = n < N_NODES;
    int nn = act ? n : N_NODES - 1;
    const uint4* rp = (const uint4*)(g_Tb + (size_t)nn * TSTRIDE);
    float a = 0.f, b = 0.f;
    #pragma unroll
    for (int k = 0; k < 16; k++){
        uint4 ch = rp[k];
        unsigned dw[4] = {ch.x, ch.y, ch.z, ch.w};
        #pragma unroll
        for (int j = 0; j < 4; j++){
            unsigned d = dw[j];
            int o = k * 8 + j * 2;
            float v0 = bu2f((unsigned short)(d & 0xFFFFu));
            float v1 = bu2f((unsigned short)(d >> 16));
            a += v0 * finz(as[o]);     b += v0 * finz(ad[o]);
            a += v1 * finz(as[o + 1]); b += v1 * finz(ad[o + 1]);
        }
    }
    if (act){
        a = finz(a); b = finz(b);
        g_es[n] = a; g_ed[n] = b;
        atomicMax(&sm[0], fkey(a));
    }
    __syncthreads();
    if (tid == 0) atomicMax(&g_gmk[base], sm[0]);
}

// ---------------- layers 1,2 GEMM: split-bf16 MFMA --------------------------
// D = Ahi*Whi + Alo*Whi + Ahi*Wlo  (error ~2^-18, numerically ~f32).
template<int NT, bool HASE>   // NT=9+E for layer1, NT=8 for layer2
__global__ __launch_bounds__(256, 3)
void k_gmm(){
    const unsigned short* Wh = HASE ? g_Wq1h : g_Wq2h;
    const unsigned short* Wl = HASE ? g_Wq1l : g_Wq2l;
    int lane = threadIdx.x & 63, wv = threadIdx.x >> 6;
    int row0 = blockIdx.x * 64 + wv * 16;
    int rl = row0 + (lane & 15);
    if (rl >= N_NODES) rl = N_NODES - 1;
    const bf16x8* Ah = (const bf16x8*)(g_Ah + (size_t)rl * ASTRIDE);
    const bf16x8* Al = (const bf16x8*)(g_Al + (size_t)rl * ASTRIDE);
    int ao = lane >> 4;

    f32x4 acc[NT] = {};
    #pragma unroll
    for (int kt = 0; kt < 5; kt++){
        bf16x8 ah = Ah[kt * 4 + ao];
        bf16x8 al = Al[kt * 4 + ao];
        const bf16x8* wh = (const bf16x8*)Wh + (size_t)(kt * NT) * 64 + lane;
        const bf16x8* wl = (const bf16x8*)Wl + (size_t)(kt * NT) * 64 + lane;
        #pragma unroll
        for (int t = 0; t < NT; t++){
            bf16x8 bh = wh[t * 64];
            bf16x8 bl = wl[t * 64];
            acc[t] = __builtin_amdgcn_mfma_f32_16x16x32_bf16(ah, bh, acc[t], 0, 0, 0);
            acc[t] = __builtin_amdgcn_mfma_f32_16x16x32_bf16(al, bh, acc[t], 0, 0, 0);
            acc[t] = __builtin_amdgcn_mfma_f32_16x16x32_bf16(ah, bl, acc[t], 0, 0, 0);
        }
    }

    int rq = row0 + (lane >> 4) * 4;
    int c  = lane & 15;
    #pragma unroll
    for (int t = 0; t < NT; t++){
        int col = t * 16 + c;
        #pragma unroll
        for (int q = 0; q < 4; q++){
            int rr = rq + q;
            if (rr >= N_NODES) continue;
            float v = finz(acc[t][q]);
            if (col < 128)            g_Tb[(size_t)rr * TSTRIDE + col] = f2bu(v);
            else if (HASE && col == 128) g_Te[rr] = v;
        }
    }
}

// ------- FUSED softmax+gather, single edge sweep ----------------------------
// Issue-slot-trimmed inner loop (R8, verified bit-exact). Z[h] denominators
// come from the zA of lanes {0,22,43} via epilogue readlanes; the E-column is
// accumulated by lane 63 whose wB == w[t,2]; H=1 uses readlane(w,t), no LDS.
// WRITEA: layers 0,1 write split-bf16 A rows; layer 2 writes f32 H.
template<int H, int O, int C, bool LEAKY, bool WRITEA>
__global__ __launch_bounds__(256)
void k_fgat(const float* __restrict__ bias, int base){
    const int CH = 64 / H;               // 21 for H=3, 64 for H=1
    __shared__ float lw[4][64];
    int wv = threadIdx.x >> 6, lane = threadIdx.x & 63;
    int n = blockIdx.x * 4 + wv;
    if (n >= N_NODES) return;
    int r0 = clampi(g_rowptr[n], 0, E_TOT);
    int r1 = clampi(g_rowptr[n + 1], r0, E_TOT);

    const int jmine = lane / H;
    const int hmine = lane - jmine * H;
    const float edm = finz(g_ed[n * H + hmine]);
    const float mxm = lrelu(finz(kinv(g_gmk[base + hmine])) + edm);  // upper bound
    const unsigned* tb = (const unsigned*)g_Tb;   // row = 64 dwords

    const int c0 = 2 * lane, c1 = 2 * lane + 1;
    const int h0 = c0 / O, h1 = c1 / O;
    float* lwp = lw[wv];

    float a0 = 0.f, a1 = 0.f, zA = 0.f, A2 = 0.f;

// per-edge body. H=3: wA/wB via LDS (2 ds_read); lane63's wB==w[t,2] feeds A2.
// H=1: weight via readlane (SGPR, no DS). t-order of every sum preserved.
#define EDGE(tt, pv, ss) { \
    float x0 = __uint_as_float((pv) << 16); \
    float x1 = __uint_as_float((pv) & 0xFFFF0000u); \
    if (H > 1){ \
        float wA = lwp[(tt) * H + h0]; \
        float wB = lwp[(tt) * H + h1]; \
        a0 += wA * x0; zA += wA; \
        a1 += wB * x1; \
        if (C > 128){ float te = finz(g_Te[ss]); A2 += wB * te; } \
    } else { \
        float wA = RL_F(w, (tt)); \
        a0 += wA * x0; zA += wA; \
        a1 += wA * x1; \
    } \
}

    for (int bse = r0; bse < r1; bse += CH){
        int m = r1 - bse; if (m > CH) m = CH;
        // phase A: cooperative weight computation (1 exp per lane)
        float w = 0.f; int sA = 0;
        if (jmine < m){
            sA = clampi(g_csrc[bse + jmine], 0, N_NODES - 1);
            w = expc(lrelu(finz(g_es[sA * H + hmine]) + edm) - mxm);
        }
        if (H > 1) lwp[lane] = w;   // wave-private row; same-wave DS order ok
        // phase B: 4 row loads in flight; src via readlane (SGPR addressing)
        int t = 0;
        for (; t + 4 <= m; t += 4){
            int s0 = RL_I(sA, (t + 0) * H);
            int s1 = RL_I(sA, (t + 1) * H);
            int s2 = RL_I(sA, (t + 2) * H);
            int s3 = RL_I(sA, (t + 3) * H);
            unsigned pv0 = tb[(size_t)s0 * 64 + lane];
            unsigned pv1 = tb[(size_t)s1 * 64 + lane];
            unsigned pv2 = tb[(size_t)s2 * 64 + lane];
            unsigned pv3 = tb[(size_t)s3 * 64 + lane];
            EDGE(t + 0, pv0, s0)
            EDGE(t + 1, pv1, s1)
            EDGE(t + 2, pv2, s2)
            EDGE(t + 3, pv3, s3)
        }
        for (; t < m; ++t){
            int s0 = RL_I(sA, t * H);
            unsigned pv0 = tb[(size_t)s0 * 64 + lane];
            EDGE(t, pv0, s0)
        }
    }
#undef EDGE

    // head-class denominators: lanes 0/22/43 hold Z[0]/Z[1]/Z[2] as zA
    // (identical accumulation sequences to the old per-lane zB/z2).
    float zB;
    if (H == 1){
        zB = zA;
    } else {
        float sz0 = RL_F(zA, 0);
        float sz1 = RL_F(zA, 22);
        float sz2 = RL_F(zA, 43);
        zB = (h1 == 0) ? sz0 : ((h1 == 1) ? sz1 : sz2);
    }

    float o0 = finz(a0 / (zA + 1e-16f)) + finz(bias[c0]);
    float o1 = finz(a1 / (zB + 1e-16f)) + finz(bias[c1]);
    if (LEAKY){ o0 = lrelu(o0); o1 = lrelu(o1); }
    o0 = finz(o0); o1 = finz(o1);
    float o2 = 0.f;
    if (C > 128){
        // meaningful on lane 63 only (wB == w[t,2], zB == Z[2] there)
        o2 = finz(A2 / (zB + 1e-16f)) + finz(bias[128]);
        if (LEAKY) o2 = lrelu(o2);
        o2 = finz(o2);
    }

    if (WRITEA){
        // split f32 -> bf16 hi + bf16 lo; pad cols 128..159 (E col + zeros)
        unsigned short hh0 = f2bu(o0), hh1 = f2bu(o1);
        unsigned short ll0 = f2bu(o0 - bu2f(hh0)), ll1 = f2bu(o1 - bu2f(hh1));
        unsigned* ah = (unsigned*)(g_Ah + (size_t)n * ASTRIDE);
        unsigned* al = (unsigned*)(g_Al + (size_t)n * ASTRIDE);
        ah[lane] = (unsigned)hh0 | ((unsigned)hh1 << 16);
        al[lane] = (unsigned)ll0 | ((unsigned)ll1 << 16);
        if (lane >= 1 && lane < 16){ ah[64 + lane] = 0u; al[64 + lane] = 0u; }
        if (C > 128){
            if (lane == 63){
                unsigned short h2 = f2bu(o2);
                ah[64] = (unsigned)h2;
                al[64] = (unsigned)f2bu(o2 - bu2f(h2));
            }
        } else if (lane == 0){
            ah[64] = 0u; al[64] = 0u;
        }
    } else {
        g_H[(size_t)n * HSTRIDE + c0] = o0;
        g_H[(size_t)n * HSTRIDE + c1] = o1;
        if (C > 128 && lane == 63) g_H[(size_t)n * HSTRIDE + 128] = o2;
    }
}

// ---------------- fused: pooling || location MLP ----------------------------
__global__ __launch_bounds__(256)
void k_poolloc(const int* __restrict__ batch, const float* __restrict__ loc,
               const float* __restrict__ Wl1, const float* __restrict__ bl1,
               const float* __restrict__ Wl2, const float* __restrict__ bl2,
               float* __restrict__ out){
    if (blockIdx.x < POOL_B){
        int c = threadIdx.x & 127;
        int n0 = blockIdx.x * 32 + (threadIdx.x >> 7) * 16;
        int bprev = -1; float acc = 0.f;
        for (int j = 0; j < 16; j++){
            int n = n0 + j;
            if (n >= N_NODES) break;
            int b = clampi(batch[n], 0, N_GRAPHS - 1);
            if (b != bprev){
                if (bprev >= 0) atomicAdd(&g_gsum[bprev * 128 + c], acc);
                acc = 0.f; bprev = b;
            }
            acc += finz(g_H[(size_t)n * HSTRIDE + c]);
        }
        if (bprev >= 0) atomicAdd(&g_gsum[bprev * 128 + c], acc);
        return;
    }
    int b = blockIdx.x - POOL_B, t = threadIdx.x;
    if (b == N_GRAPHS){   // per-graph node counts via binary search
        if (t < N_GRAPHS){
            int lo = 0, hi = N_NODES;
            while (lo < hi){ int mid = (lo + hi) >> 1; if (batch[mid] <  t) lo = mid + 1; else hi = mid; }
            int start = lo;
            lo = 0; hi = N_NODES;
            while (lo < hi){ int mid = (lo + hi) >> 1; if (batch[mid] <= t) lo = mid + 1; else hi = mid; }
            g_gcnt[t] = (float)(lo - start);
        }
        return;
    }
    __shared__ float hs[256];
    float w0 = finz(Wl1[t]);
    float w1 = finz(Wl1[256 + t]);
    float bb = finz(bl1[t]);
    float s = 0.f;
    #pragma unroll 5
    for (int l = 0; l < N_LOCS; l++){
        float x0 = finz(loc[((size_t)b * N_LOCS + l) * 2]);
        float x1 = finz(loc[((size_t)b * N_LOCS + l) * 2 + 1]);
        s += tanhf(x0 * w0 + x1 * w1 + bb);
    }
    hs[t] = s;
    __syncthreads();
    if (t < 128){
        float acc = 0.f;
        #pragma unroll 8
        for (int j = 0; j < 256; j++) acc += hs[j] * finz(Wl2[(size_t)j * 128 + t]);
        out[(size_t)b * 256 + 128 + t] = finz(acc * (1.f / (float)N_LOCS) + finz(bl2[t]));
    }
}

// output is float32 (established r13/r14)
__global__ void k_fin(float* __restrict__ out){
    int idx = blockIdx.x * blockDim.x + threadIdx.x;
    if (idx >= N_GRAPHS * 128) return;
    int b = idx >> 7, c = idx & 127;
    out[b * 256 + c] = finz(finz(g_gsum[idx]) / fmaxf(g_gcnt[b], 1.f));
}

// ---------------- launch ----------------
extern "C" void kernel_launch(void* const* d_in, const int* in_sizes, int n_in,
                              void* d_out, int out_size, void* d_ws, size_t ws_size,
                              hipStream_t stream){
    static const int want[20] = {300000, 6400, 1600000, 50000,
                                 774, 129, 129, 129,
                                 16641, 129, 129, 129,
                                 16512, 128, 128, 128,
                                 512, 256, 32768, 128};
    const void* P[20];
    bool assigned[20];
    for (int s = 0; s < 20; s++){ P[s] = nullptr; assigned[s] = false; }
    bool ok = (n_in == 20);
    if (ok){
        for (int i = 0; i < 20; i++){
            int sz = in_sizes[i], hit = -1;
            for (int s = 0; s < 20; s++)
                if (!assigned[s] && want[s] == sz){ hit = s; break; }
            if (hit < 0){ ok = false; break; }
            P[hit] = d_in[i]; assigned[hit] = true;
        }
        for (int s = 0; s < 20 && ok; s++) if (!assigned[s]) ok = false;
    }
    if (!ok) for (int s = 0; s < 20 && s < n_in; s++) P[s] = d_in[s];

    const float* x    = (const float*)P[0];
    const float* loc  = (const float*)P[1];
    const int*   ei   = (const int*)  P[2];
    const int*   batch= (const int*)  P[3];
    const float* W0   = (const float*)P[4];
    const float* as0  = (const float*)P[5];
    const float* ad0  = (const float*)P[6];
    const float* b0   = (const float*)P[7];
    const float* W1   = (const float*)P[8];
    const float* as1  = (const float*)P[9];
    const float* ad1  = (const float*)P[10];
    const float* b1   = (const float*)P[11];
    const float* W2   = (const float*)P[12];
    const float* as2  = (const float*)P[13];
    const float* ad2  = (const float*)P[14];
    const float* b2   = (const float*)P[15];
    const float* Wl1  = (const float*)P[16];
    const float* bl1  = (const float*)P[17];
    const float* Wl2  = (const float*)P[18];
    const float* bl2  = (const float*)P[19];
    float* out = (float*)d_out;
    (void)d_ws; (void)ws_size; (void)out_size;

    const int MFMA_B  = (N_NODES + 63) / 64;   // 64 rows/block (4 waves x 16)
    const int GB = (N_NODES + 3) / 4;

    k_pre    <<<(PRE_TOT + 255) / 256, 256, 0, stream>>>(W0, W1, W2);
    k_g0deg  <<<EB_B + GEMM0_B, 256, 0, stream>>>(x, ei);   // deg+slot || gemm0
    k_scan1  <<<SCAN_B, 256, 0, stream>>>();
    k_scan23 <<<SCAN_B, 256, 0, stream>>>();
    k_esfill <<<EB_B + ESED3_B, 256, 0, stream>>>(as0, ad0, ei); // fill || esed0

    // layer 0
    k_fgat<3, 43, 129, true, true><<<GB, 256, 0, stream>>>(b0, 0);

    // layer 1 (MFMA split-bf16)
    k_gmm<9, true><<<MFMA_B, 256, 0, stream>>>();
    k_esed3<<<ESED3_B, 256, 0, stream>>>(as1, ad1, 3);
    k_fgat<3, 43, 129, true, true><<<GB, 256, 0, stream>>>(b1, 3);

    // layer 2 (MFMA split-bf16)
    k_gmm<8, false><<<MFMA_B, 256, 0, stream>>>();
    k_esedR<<<(N_NODES + 255) / 256, 256, 0, stream>>>(as2, ad2, 6);
    k_fgat<1, 128, 128, false, false><<<GB, 256, 0, stream>>>(b2, 6);

    // pooling + location + output
    k_poolloc<<<POOL_B + N_GRAPHS + 1, 256, 0, stream>>>(batch, loc, Wl1, bl1, Wl2, bl2, out);
    k_fin  <<<(N_GRAPHS * 128 + 255) / 256, 256, 0, stream>>>(out);
}